// Round 5
// baseline (148.533 us; speedup 1.0000x reference)
//
#include <hip/hip_runtime.h>

#define BN 4096
#define DIM 256
#define NBLK 32              // 4096/128 row-blocks
#define NPAIR 528            // NBLK*(NBLK+1)/2 upper-tri block pairs
#define MARGIN_F 0.3f
#define NEG_FILL_F 1e9f

typedef __attribute__((ext_vector_type(8))) __bf16 bf16x8;
typedef __attribute__((ext_vector_type(4))) float f32x4;

// fp32 -> bf16 round-to-nearest-even (inputs are normal floats, no NaN/Inf)
__device__ __forceinline__ ushort f2bf(float x) {
    unsigned u = __float_as_uint(x);
    return (ushort)((u + 0x7FFFu + ((u >> 16) & 1u)) >> 16);
}
__device__ __forceinline__ float bf2f(ushort b) {
    return __uint_as_float(((unsigned)b) << 16);
}

// async global->LDS, 16B per lane; LDS dest: wave-uniform base + lane*16
__device__ __forceinline__ void gld_lds16(const void* g, void* l) {
    __builtin_amdgcn_global_load_lds(
        (const __attribute__((address_space(1))) unsigned int*)g,
        (__attribute__((address_space(3))) unsigned int*)l, 16, 0, 0);
}

// ---------------- prep: norms + hp/hn init + hist (block 0) + bf16 hi/lo split ----
// Ehi/Elo global layout is chunk-major: [kc = k/8][row][8 bf16], 16B per (kc,row).
__global__ __launch_bounds__(256) void tl_prep(const float* __restrict__ E,
                                               const int* __restrict__ labels,
                                               float* __restrict__ norms,
                                               unsigned* __restrict__ hp,
                                               unsigned* __restrict__ hn,
                                               int* __restrict__ hist,
                                               ushort* __restrict__ Ehi,
                                               ushort* __restrict__ Elo) {
    const int tid  = threadIdx.x;
    const int lane = tid & 63;
    const int row  = blockIdx.x * 4 + (tid >> 6);

    float4 v = reinterpret_cast<const float4*>(E + (size_t)row * DIM)[lane];
    float f[4] = {v.x, v.y, v.z, v.w};
    ushort hb[4], lb[4];
    float s = 0.0f;
    #pragma unroll
    for (int q = 0; q < 4; ++q) {
        s += f[q] * f[q];
        hb[q] = f2bf(f[q]);
        lb[q] = f2bf(f[q] - bf2f(hb[q]));
    }
    // lane holds k = lane*4..lane*4+3 -> chunk kc = lane/2, half = lane&1
    const int kc = lane >> 1, half = lane & 1;
    const size_t co = (((size_t)(kc * BN + row)) << 3) + (size_t)(half * 4);
    *reinterpret_cast<ushort4*>(Ehi + co) = make_ushort4(hb[0], hb[1], hb[2], hb[3]);
    *reinterpret_cast<ushort4*>(Elo + co) = make_ushort4(lb[0], lb[1], lb[2], lb[3]);

    #pragma unroll
    for (int m = 32; m; m >>= 1) s += __shfl_xor(s, m, 64);
    if (lane == 0) {
        norms[row] = s;
        hp[row] = 0u;                              // identity for max over d>=0
        hn[row] = __float_as_uint(NEG_FILL_F);     // ref's NEG_FILL
    }

    // label histogram, single block (no cross-block ordering needed)
    __shared__ int lh[512];
    if (blockIdx.x == 0) {
        for (int i = tid; i < 512; i += 256) lh[i] = 0;
        __syncthreads();
        for (int i = tid; i < BN; i += 256) atomicAdd(&lh[labels[i]], 1);
        __syncthreads();
        for (int i = tid; i < 512; i += 256) hist[i] = lh[i];
    }
}

// ---------------- main: split-bf16 MFMA Gram + fused distance/masked min-max ------
// One block per (pair, col-half): 128 rows x 64 cols. 4 waves, each 64x32.
// LDS 2 x 24 KB (double-buffered) -> 3 blocks/CU co-resident, 12 waves/CU.
__global__ __launch_bounds__(256, 3) void tl_main(const ushort* __restrict__ Ehi,
                                                  const ushort* __restrict__ Elo,
                                                  const int* __restrict__ labels,
                                                  const float* __restrict__ norms,
                                                  unsigned* __restrict__ hp,
                                                  unsigned* __restrict__ hn) {
    // Per buffer (ushort elems): Ahi rows 0..511 (kc*128+m), Alo 512..1023,
    // Bhi 1024..1279 (kc*64+m), Blo 1280..1535; each row = 8 bf16 = 16B. 24 KB.
    __shared__ __align__(16) ushort smem[2][12288];

    const int tid  = threadIdx.x;
    const int lane = tid & 63;
    const int wave = tid >> 6;
    const int wy = wave >> 1, wx = wave & 1;      // wave tile: rows wy*64, cols wx*32
    const int quad = lane >> 4, l15 = lane & 15;

    // decode blockIdx -> (pair, half) -> (ib <= jb), col-half
    const int pair = blockIdx.x >> 1;
    const int half = blockIdx.x & 1;
    int t = pair, ib = 0, off = 0;
    while (off + (NBLK - ib) <= t) { off += NBLK - ib; ++ib; }
    const int jb = ib + (t - off);
    const int i0  = ib * 128;
    const int j0c = jb * 128 + half * 64;

    f32x4 acc[4][2];
    #pragma unroll
    for (int r = 0; r < 4; ++r)
        #pragma unroll
        for (int c = 0; c < 2; ++c)
            acc[r][c] = (f32x4){0.f, 0.f, 0.f, 0.f};

    // stage one 32-k slab (A 128 rows hi/lo + B 64 cols hi/lo) into buffer `buf`
    auto stage = [&](int kb, int buf) {
        #pragma unroll
        for (int s = 0; s < 6; ++s) {
            const int idx = s * 256 + tid;           // 1536 16B chunks
            const ushort* src;
            int kc, m, base;
            if (idx < 1024) {                        // A: 512 hi + 512 lo
                src = (idx < 512) ? Ehi : Elo;
                const int r9 = idx & 511;
                kc = r9 >> 7; m = r9 & 127; base = i0;
            } else {                                 // B: 256 hi + 256 lo
                src = (idx < 1280) ? Ehi : Elo;
                const int r8 = idx & 255;
                kc = r8 >> 6; m = r8 & 63; base = j0c;
            }
            src += ((size_t)((kb * 4 + kc) * BN + base + m)) << 3;
            gld_lds16(src, &smem[buf][idx << 3]);
        }
    };

    stage(0, 0);
    for (int kb = 0; kb < DIM / 32; ++kb) {
        const int buf = kb & 1;
        __syncthreads();                   // drain stage(kb); protect buf^1 readers
        if (kb + 1 < DIM / 32) stage(kb + 1, buf ^ 1);

        const ushort* sb = &smem[buf][0];
        bf16x8 ah[4], al[4];
        #pragma unroll
        for (int r = 0; r < 4; ++r) {
            const int mi = wy * 64 + r * 16 + l15;
            ah[r] = *reinterpret_cast<const bf16x8*>(&sb[(quad * 128 + mi) * 8]);
            al[r] = *reinterpret_cast<const bf16x8*>(&sb[(512 + quad * 128 + mi) * 8]);
        }
        #pragma unroll
        for (int c = 0; c < 2; ++c) {
            const int ni = wx * 32 + c * 16 + l15;
            bf16x8 bh = *reinterpret_cast<const bf16x8*>(&sb[(1024 + quad * 64 + ni) * 8]);
            bf16x8 bl = *reinterpret_cast<const bf16x8*>(&sb[(1280 + quad * 64 + ni) * 8]);
            #pragma unroll
            for (int r = 0; r < 4; ++r) {
                acc[r][c] = __builtin_amdgcn_mfma_f32_16x16x32_bf16(ah[r], bh, acc[r][c], 0, 0, 0);
                acc[r][c] = __builtin_amdgcn_mfma_f32_16x16x32_bf16(ah[r], bl, acc[r][c], 0, 0, 0);
                acc[r][c] = __builtin_amdgcn_mfma_f32_16x16x32_bf16(al[r], bh, acc[r][c], 0, 0, 0);
            }
        }
    }

    // ---- epilogue: dots -> distances -> masked row & col stats ----
    // C layout (16x16x32): col = lane&15, row = quad*4 + reg  [m89/m91]
    const int rowBase = i0 + wy * 64;
    const int colBase = j0c + wx * 32;

    float nrow[4][4]; int lrow[4][4];
    #pragma unroll
    for (int r = 0; r < 4; ++r)
        #pragma unroll
        for (int e = 0; e < 4; ++e) {
            const int g = rowBase + r * 16 + quad * 4 + e;
            nrow[r][e] = norms[g];
            lrow[r][e] = labels[g];
        }
    float ncol[2]; int lcol[2];
    #pragma unroll
    for (int c = 0; c < 2; ++c) {
        const int g = colBase + c * 16 + l15;
        ncol[c] = norms[g];
        lcol[c] = labels[g];
    }

    float rmax[4][4], rmin[4][4], cmax[2], cmin[2];
    #pragma unroll
    for (int r = 0; r < 4; ++r)
        #pragma unroll
        for (int e = 0; e < 4; ++e) { rmax[r][e] = 0.0f; rmin[r][e] = NEG_FILL_F; }
    #pragma unroll
    for (int c = 0; c < 2; ++c) { cmax[c] = 0.0f; cmin[c] = NEG_FILL_F; }

    #pragma unroll
    for (int c = 0; c < 2; ++c) {
        const int gcol = colBase + c * 16 + l15;
        #pragma unroll
        for (int r = 0; r < 4; ++r) {
            #pragma unroll
            for (int e = 0; e < 4; ++e) {
                const int grow = rowBase + r * 16 + quad * 4 + e;
                float d2 = nrow[r][e] + ncol[c] - 2.0f * acc[r][c][e];
                d2 = fmaxf(d2, 0.0f);
                const float d = (d2 > 0.0f) ? sqrtf(d2) : 0.0f;
                if (lrow[r][e] == lcol[c]) {
                    if (grow != gcol) {
                        rmax[r][e] = fmaxf(rmax[r][e], d);
                        cmax[c]    = fmaxf(cmax[c], d);
                    }
                } else {
                    rmin[r][e] = fminf(rmin[r][e], d);
                    cmin[c]    = fminf(cmin[c], d);
                }
            }
        }
    }

    #pragma unroll
    for (int m = 1; m <= 8; m <<= 1) {          // row stats across lane bits 0..3
        #pragma unroll
        for (int r = 0; r < 4; ++r)
            #pragma unroll
            for (int e = 0; e < 4; ++e) {
                rmax[r][e] = fmaxf(rmax[r][e], __shfl_xor(rmax[r][e], m, 64));
                rmin[r][e] = fminf(rmin[r][e], __shfl_xor(rmin[r][e], m, 64));
            }
    }
    #pragma unroll
    for (int m = 16; m <= 32; m <<= 1) {        // col stats across quads
        #pragma unroll
        for (int c = 0; c < 2; ++c) {
            cmax[c] = fmaxf(cmax[c], __shfl_xor(cmax[c], m, 64));
            cmin[c] = fminf(cmin[c], __shfl_xor(cmin[c], m, 64));
        }
    }

    // block-level combine in LDS (reuse staging memory), then global atomics
    unsigned* srhp = reinterpret_cast<unsigned*>(&smem[0][0]);  // [128]
    unsigned* srhn = srhp + 128;                                // [128]
    unsigned* schp = srhp + 256;                                // [64]
    unsigned* schn = srhp + 320;                                // [64]
    __syncthreads();                  // all frag reads done; smem reusable
    if (tid < 128) {
        srhp[tid] = 0u;
        srhn[tid] = __float_as_uint(NEG_FILL_F);
    }
    if (tid < 64) {
        schp[tid] = 0u;
        schn[tid] = __float_as_uint(NEG_FILL_F);
    }
    __syncthreads();
    if (l15 == 0) {   // lanes 0,16,32,48 hold row results for their quad
        #pragma unroll
        for (int r = 0; r < 4; ++r)
            #pragma unroll
            for (int e = 0; e < 4; ++e) {
                const int lr = wy * 64 + r * 16 + quad * 4 + e;
                atomicMax(&srhp[lr], __float_as_uint(rmax[r][e]));
                atomicMin(&srhn[lr], __float_as_uint(rmin[r][e]));
            }
    }
    if (quad == 0) {  // lanes 0..15 hold col results
        #pragma unroll
        for (int c = 0; c < 2; ++c) {
            const int lc = wx * 32 + c * 16 + l15;
            atomicMax(&schp[lc], __float_as_uint(cmax[c]));
            atomicMin(&schn[lc], __float_as_uint(cmin[c]));
        }
    }
    __syncthreads();
    if (tid < 128) {
        atomicMax(&hp[i0 + tid], srhp[tid]);   // uint order == float order for x>=0
        atomicMin(&hn[i0 + tid], srhn[tid]);
    }
    if (tid < 64) {
        atomicMax(&hp[j0c + tid], schp[tid]);  // transposed contribution (d symmetric)
        atomicMin(&hn[j0c + tid], schn[tid]);
    }
}

// ---------------- final scalar reduction ----------------
__global__ __launch_bounds__(1024) void tl_finish(const unsigned* __restrict__ hp,
                                                  const unsigned* __restrict__ hn,
                                                  const int* __restrict__ labels,
                                                  const int* __restrict__ hist,
                                                  float* __restrict__ out) {
    __shared__ float ssum[16];
    __shared__ float scnt[16];
    const int t = threadIdx.x;
    float sum = 0.0f, cnt = 0.0f;
    for (int i = t; i < BN; i += 1024) {
        const int h = hist[labels[i]];
        const bool valid = (h >= 2) && (h < BN);   // has_pos && has_neg
        const float per = fmaxf(__uint_as_float(hp[i]) - __uint_as_float(hn[i]) + MARGIN_F, 0.0f);
        if (valid) { sum += per; cnt += 1.0f; }
    }
    #pragma unroll
    for (int m = 32; m; m >>= 1) {
        sum += __shfl_xor(sum, m, 64);
        cnt += __shfl_xor(cnt, m, 64);
    }
    const int wid = t >> 6;
    if ((t & 63) == 0) { ssum[wid] = sum; scnt[wid] = cnt; }
    __syncthreads();
    if (t == 0) {
        float S = 0.0f, C = 0.0f;
        #pragma unroll
        for (int w = 0; w < 16; ++w) { S += ssum[w]; C += scnt[w]; }
        out[0] = (C > 0.0f) ? (S / fmaxf(C, 1.0f)) : 0.0f;
    }
}

extern "C" void kernel_launch(void* const* d_in, const int* in_sizes, int n_in,
                              void* d_out, int out_size, void* d_ws, size_t ws_size,
                              hipStream_t stream) {
    const float* E      = (const float*)d_in[0];
    const int*   labels = (const int*)d_in[1];

    float*    ws    = (float*)d_ws;
    float*    norms = ws;                          // [4096] f32
    unsigned* hp    = (unsigned*)(ws + 4096);      // [4096] u32
    unsigned* hn    = (unsigned*)(ws + 8192);      // [4096] u32
    int*      hist  = (int*)(ws + 12288);          // [512]  i32
    ushort*   Ehi   = (ushort*)(ws + 16384);       // [32][4096][8] bf16 = 2 MB
    ushort*   Elo   = Ehi + (size_t)BN * DIM;      // 2 MB

    tl_prep<<<BN / 4, 256, 0, stream>>>(E, labels, norms, hp, hn, hist, Ehi, Elo);
    tl_main<<<NPAIR * 2, 256, 0, stream>>>(Ehi, Elo, labels, norms, hp, hn);
    tl_finish<<<1, 1024, 0, stream>>>(hp, hn, labels, hist, (float*)d_out);
}

// Round 6
// 107.057 us; speedup vs baseline: 1.3874x; 1.3874x over previous
//
#include <hip/hip_runtime.h>

#define BN 4096
#define DIM 256
#define NBLK 32              // 4096/128 row-blocks
#define NPAIR 528            // NBLK*(NBLK+1)/2 upper-tri block pairs
#define MARGIN_F 0.3f
#define NEG_FILL_F 1e9f
#define HP_SENT_BITS 0xBF800000  // bits of -1.0f: "no positive seen"

typedef __attribute__((ext_vector_type(8))) __bf16 bf16x8;
typedef __attribute__((ext_vector_type(4))) float f32x4;

// fp32 -> bf16 round-to-nearest-even (inputs are normal floats, no NaN/Inf)
__device__ __forceinline__ ushort f2bf(float x) {
    unsigned u = __float_as_uint(x);
    return (ushort)((u + 0x7FFFu + ((u >> 16) & 1u)) >> 16);
}
__device__ __forceinline__ float bf2f(ushort b) {
    return __uint_as_float(((unsigned)b) << 16);
}

// async global->LDS, 16B per lane; LDS dest: wave-uniform base + lane*16
__device__ __forceinline__ void gld_lds16(const void* g, void* l) {
    __builtin_amdgcn_global_load_lds(
        (const __attribute__((address_space(1))) unsigned int*)g,
        (__attribute__((address_space(3))) unsigned int*)l, 16, 0, 0);
}

// ---------------- prep: norms + red zero + bf16 hi/lo split ----------------
// Ehi/Elo global layout is chunk-major: [kc = k/8][row][8 bf16], 16B per (kc,row).
__global__ __launch_bounds__(256) void tl_prep(const float* __restrict__ E,
                                               float* __restrict__ norms,
                                               float* __restrict__ red,
                                               ushort* __restrict__ Ehi,
                                               ushort* __restrict__ Elo) {
    const int tid  = threadIdx.x;
    const int lane = tid & 63;
    const int row  = blockIdx.x * 4 + (tid >> 6);

    float4 v = reinterpret_cast<const float4*>(E + (size_t)row * DIM)[lane];
    float f[4] = {v.x, v.y, v.z, v.w};
    ushort hb[4], lb[4];
    float s = 0.0f;
    #pragma unroll
    for (int q = 0; q < 4; ++q) {
        s += f[q] * f[q];
        hb[q] = f2bf(f[q]);
        lb[q] = f2bf(f[q] - bf2f(hb[q]));
    }
    // lane holds k = lane*4..lane*4+3 -> chunk kc = lane/2, half = lane&1
    const int kc = lane >> 1, half = lane & 1;
    const size_t co = (((size_t)(kc * BN + row)) << 3) + (size_t)(half * 4);
    *reinterpret_cast<ushort4*>(Ehi + co) = make_ushort4(hb[0], hb[1], hb[2], hb[3]);
    *reinterpret_cast<ushort4*>(Elo + co) = make_ushort4(lb[0], lb[1], lb[2], lb[3]);

    #pragma unroll
    for (int m = 32; m; m >>= 1) s += __shfl_xor(s, m, 64);
    if (lane == 0) norms[row] = s;
    if (blockIdx.x == 0 && tid == 0) { red[0] = 0.0f; red[1] = 0.0f; }
}

// ---------------- main: split-bf16 MFMA Gram + fused distance/masked min-max ------
// One block per upper-tri 128x128 pair. 4 waves, each a 64x64 sub-tile.
// Results leave via PLAIN stores to collision-free partial slots (no global atomics):
//   row-part of pair (ib,jb)  -> pHP/pHN[jb*BN + i]   (i in block ib)
//   col-part of pair (ib,jb)  -> pHP/pHN[ib*BN + j]   (j in block jb)
//   diagonal (ib==jb): combined locally, single write -> slot ib.
// For target block R, slot s has exactly one writer; all 32 slots covered.
__global__ __launch_bounds__(256) void tl_main(const ushort* __restrict__ Ehi,
                                               const ushort* __restrict__ Elo,
                                               const int* __restrict__ labels,
                                               const float* __restrict__ norms,
                                               float* __restrict__ pHP,
                                               float* __restrict__ pHN) {
    // Per buffer: [part: Ahi,Alo,Bhi,Blo][kc 0..3][m 0..127][8 bf16] = 32 KB
    __shared__ __align__(16) ushort smem[2][16384];

    const int tid  = threadIdx.x;
    const int lane = tid & 63;
    const int wave = tid >> 6;
    const int wy = wave >> 1, wx = wave & 1;
    const int quad = lane >> 4, l15 = lane & 15;

    // decode blockIdx -> (ib <= jb) upper-tri pair
    int t = blockIdx.x, ib = 0, off = 0;
    while (off + (NBLK - ib) <= t) { off += NBLK - ib; ++ib; }
    const int jb = ib + (t - off);
    const int i0 = ib * 128, j0 = jb * 128;

    f32x4 acc[4][4];
    #pragma unroll
    for (int r = 0; r < 4; ++r)
        #pragma unroll
        for (int c = 0; c < 4; ++c)
            acc[r][c] = (f32x4){0.f, 0.f, 0.f, 0.f};

    auto stage = [&](int kb, int buf) {
        #pragma unroll
        for (int s = 0; s < 8; ++s) {
            const int idx  = s * 256 + tid;          // 2048 16B chunks
            const int part = idx >> 9;               // 0:Ahi 1:Alo 2:Bhi 3:Blo
            const int kc   = (idx >> 7) & 3;
            const int m    = idx & 127;
            const ushort* src = (part & 1) ? Elo : Ehi;
            const int     base = (part < 2) ? i0 : j0;
            src += ((size_t)((kb * 4 + kc) * BN + base + m)) << 3;
            gld_lds16(src, &smem[buf][idx << 3]);
        }
    };

    stage(0, 0);
    for (int kb = 0; kb < DIM / 32; ++kb) {
        const int buf = kb & 1;
        __syncthreads();                   // drain stage(kb); protect buf^1 readers
        if (kb + 1 < DIM / 32) stage(kb + 1, buf ^ 1);

        const ushort* sb = &smem[buf][0];
        bf16x8 ah[4], al[4];
        #pragma unroll
        for (int r = 0; r < 4; ++r) {
            const int mi = wy * 64 + r * 16 + l15;
            ah[r] = *reinterpret_cast<const bf16x8*>(&sb[(0 * 512 + quad * 128 + mi) * 8]);
            al[r] = *reinterpret_cast<const bf16x8*>(&sb[(1 * 512 + quad * 128 + mi) * 8]);
        }
        #pragma unroll
        for (int c = 0; c < 4; ++c) {
            const int ni = wx * 64 + c * 16 + l15;
            bf16x8 bh = *reinterpret_cast<const bf16x8*>(&sb[(2 * 512 + quad * 128 + ni) * 8]);
            bf16x8 bl = *reinterpret_cast<const bf16x8*>(&sb[(3 * 512 + quad * 128 + ni) * 8]);
            #pragma unroll
            for (int r = 0; r < 4; ++r) {
                acc[r][c] = __builtin_amdgcn_mfma_f32_16x16x32_bf16(ah[r], bh, acc[r][c], 0, 0, 0);
                acc[r][c] = __builtin_amdgcn_mfma_f32_16x16x32_bf16(ah[r], bl, acc[r][c], 0, 0, 0);
                acc[r][c] = __builtin_amdgcn_mfma_f32_16x16x32_bf16(al[r], bh, acc[r][c], 0, 0, 0);
            }
        }
    }

    // ---- epilogue: dots -> distances -> masked row & col stats ----
    // C layout (16x16x32): col = lane&15, row = quad*4 + reg  [m89/m91]
    const int rowBase = i0 + wy * 64;
    const int colBase = j0 + wx * 64;

    float nrow[4][4]; int lrow[4][4];
    #pragma unroll
    for (int r = 0; r < 4; ++r)
        #pragma unroll
        for (int e = 0; e < 4; ++e) {
            const int g = rowBase + r * 16 + quad * 4 + e;
            nrow[r][e] = norms[g];
            lrow[r][e] = labels[g];
        }
    float ncol[4]; int lcol[4];
    #pragma unroll
    for (int c = 0; c < 4; ++c) {
        const int g = colBase + c * 16 + l15;
        ncol[c] = norms[g];
        lcol[c] = labels[g];
    }

    float rmax[4][4], rmin[4][4], cmax[4], cmin[4];
    #pragma unroll
    for (int r = 0; r < 4; ++r)
        #pragma unroll
        for (int e = 0; e < 4; ++e) { rmax[r][e] = -1.0f; rmin[r][e] = NEG_FILL_F; }
    #pragma unroll
    for (int c = 0; c < 4; ++c) { cmax[c] = -1.0f; cmin[c] = NEG_FILL_F; }

    #pragma unroll
    for (int c = 0; c < 4; ++c) {
        const int gcol = colBase + c * 16 + l15;
        #pragma unroll
        for (int r = 0; r < 4; ++r) {
            #pragma unroll
            for (int e = 0; e < 4; ++e) {
                const int grow = rowBase + r * 16 + quad * 4 + e;
                float d2 = nrow[r][e] + ncol[c] - 2.0f * acc[r][c][e];
                d2 = fmaxf(d2, 0.0f);
                const float d = (d2 > 0.0f) ? sqrtf(d2) : 0.0f;
                if (lrow[r][e] == lcol[c]) {
                    if (grow != gcol) {
                        rmax[r][e] = fmaxf(rmax[r][e], d);
                        cmax[c]    = fmaxf(cmax[c], d);
                    }
                } else {
                    rmin[r][e] = fminf(rmin[r][e], d);
                    cmin[c]    = fminf(cmin[c], d);
                }
            }
        }
    }

    #pragma unroll
    for (int m = 1; m <= 8; m <<= 1) {          // row stats across lane bits 0..3
        #pragma unroll
        for (int r = 0; r < 4; ++r)
            #pragma unroll
            for (int e = 0; e < 4; ++e) {
                rmax[r][e] = fmaxf(rmax[r][e], __shfl_xor(rmax[r][e], m, 64));
                rmin[r][e] = fminf(rmin[r][e], __shfl_xor(rmin[r][e], m, 64));
            }
    }
    #pragma unroll
    for (int m = 16; m <= 32; m <<= 1) {        // col stats across quads
        #pragma unroll
        for (int c = 0; c < 4; ++c) {
            cmax[c] = fmaxf(cmax[c], __shfl_xor(cmax[c], m, 64));
            cmin[c] = fminf(cmin[c], __shfl_xor(cmin[c], m, 64));
        }
    }

    // block-level combine in LDS (CU-local atomics; signed-int encoding so the
    // -1.0f sentinel orders correctly), then PLAIN global stores to partial slots.
    int*      srhp = reinterpret_cast<int*>(&smem[0][0]);        // [128]
    unsigned* srhn = reinterpret_cast<unsigned*>(srhp + 128);
    int*      schp = srhp + 256;
    unsigned* schn = reinterpret_cast<unsigned*>(srhp + 384);
    __syncthreads();                  // all frag reads done; smem reusable
    if (tid < 128) {
        srhp[tid] = (int)HP_SENT_BITS;
        srhn[tid] = __float_as_uint(NEG_FILL_F);
        schp[tid] = (int)HP_SENT_BITS;
        schn[tid] = __float_as_uint(NEG_FILL_F);
    }
    __syncthreads();
    if (l15 == 0) {   // lanes 0,16,32,48 hold row results for their quad
        #pragma unroll
        for (int r = 0; r < 4; ++r)
            #pragma unroll
            for (int e = 0; e < 4; ++e) {
                const int lr = wy * 64 + r * 16 + quad * 4 + e;
                atomicMax(&srhp[lr], __float_as_int(rmax[r][e]));
                atomicMin(&srhn[lr], __float_as_uint(rmin[r][e]));
            }
    }
    if (quad == 0) {  // lanes 0..15 hold col results
        #pragma unroll
        for (int c = 0; c < 4; ++c) {
            const int lc = wx * 64 + c * 16 + l15;
            atomicMax(&schp[lc], __float_as_int(cmax[c]));
            atomicMin(&schn[lc], __float_as_uint(cmin[c]));
        }
    }
    __syncthreads();
    if (tid < 128) {
        float rp = __int_as_float(srhp[tid]);
        float rn = __uint_as_float(srhn[tid]);
        const float cp = __int_as_float(schp[tid]);
        const float cn = __uint_as_float(schn[tid]);
        if (ib == jb) {
            // diagonal: row- and col-parts target the same slot; combine locally
            pHP[(size_t)jb * BN + i0 + tid] = fmaxf(rp, cp);
            pHN[(size_t)jb * BN + i0 + tid] = fminf(rn, cn);
        } else {
            pHP[(size_t)jb * BN + i0 + tid] = rp;   // row-part -> slot jb
            pHN[(size_t)jb * BN + i0 + tid] = rn;
            pHP[(size_t)ib * BN + j0 + tid] = cp;   // col-part -> slot ib
            pHN[(size_t)ib * BN + j0 + tid] = cn;
        }
    }
}

// ---------------- reduce: fold 32 partial slots per row, accumulate loss ---------
__global__ __launch_bounds__(256) void tl_reduce(const float* __restrict__ pHP,
                                                 const float* __restrict__ pHN,
                                                 float* __restrict__ red) {
    const int i = blockIdx.x * 256 + threadIdx.x;    // one row per thread
    float hp = -1.0f, hn = NEG_FILL_F;
    #pragma unroll
    for (int s = 0; s < NBLK; ++s) {
        hp = fmaxf(hp, pHP[(size_t)s * BN + i]);     // coalesced per wave
        hn = fminf(hn, pHN[(size_t)s * BN + i]);
    }
    // has_pos <=> some positive seen (sentinel -1 otherwise); has_neg <=> hn updated
    const bool valid = (hp >= 0.0f) && (hn < NEG_FILL_F);
    const float per = fmaxf(hp - hn + MARGIN_F, 0.0f);
    float s_ = valid ? per : 0.0f;
    float c_ = valid ? 1.0f : 0.0f;
    #pragma unroll
    for (int m = 32; m; m >>= 1) {
        s_ += __shfl_xor(s_, m, 64);
        c_ += __shfl_xor(c_, m, 64);
    }
    __shared__ float as_[4], ac_[4];
    const int wid = threadIdx.x >> 6;
    if ((threadIdx.x & 63) == 0) { as_[wid] = s_; ac_[wid] = c_; }
    __syncthreads();
    if (threadIdx.x == 0) {
        float S = as_[0] + as_[1] + as_[2] + as_[3];
        float C = ac_[0] + ac_[1] + ac_[2] + ac_[3];
        atomicAdd(&red[0], S);            // 16 atomics total -> negligible
        atomicAdd(&red[1], C);
    }
}

__global__ void tl_final(const float* __restrict__ red, float* __restrict__ out) {
    const float S = red[0], C = red[1];
    out[0] = (C > 0.0f) ? (S / fmaxf(C, 1.0f)) : 0.0f;
}

extern "C" void kernel_launch(void* const* d_in, const int* in_sizes, int n_in,
                              void* d_out, int out_size, void* d_ws, size_t ws_size,
                              hipStream_t stream) {
    const float* E      = (const float*)d_in[0];
    const int*   labels = (const int*)d_in[1];

    float*  ws    = (float*)d_ws;
    float*  norms = ws;                            // [4096] f32
    float*  red   = ws + 4096;                     // [2] f32 (sum, cnt)
    float*  pHP   = ws + 8192;                     // [32][4096] f32 = 512 KB
    float*  pHN   = ws + 8192 + NBLK * BN;         // [32][4096] f32 = 512 KB
    ushort* Ehi   = (ushort*)(ws + 8192 + 2 * NBLK * BN);  // [32][4096][8] bf16 = 2 MB
    ushort* Elo   = Ehi + (size_t)BN * DIM;        // 2 MB

    tl_prep<<<BN / 4, 256, 0, stream>>>(E, norms, red, Ehi, Elo);
    tl_main<<<NPAIR, 256, 0, stream>>>(Ehi, Elo, labels, norms, pHP, pHN);
    tl_reduce<<<BN / 256, 256, 0, stream>>>(pHP, pHN, red);
    tl_final<<<1, 1, 0, stream>>>(red, (float*)d_out);
}